// Round 4
// baseline (781.094 us; speedup 1.0000x reference)
//
#include <hip/hip_runtime.h>

#define NUM_VOXELS     1000000
#define N_POINTS       1500000
#define TOTAL_PROP_PTS 1000000
#define NUM_PROPOSALS  2048
#define IN_CH          134
#define M_OUT          16

#define G1 ((NUM_VOXELS + 255) / 256)      // gemm blocks (3907)
#define GP ((TOTAL_PROP_PTS + 255) / 256)  // prep blocks (3907)

// ---------------------------------------------------------------------------
// v5 (r3 post-mortem: K2 rewrite moved nothing -> K1 owns the ~250 us
// kernel budget; attack its TRAFFIC, which is also a diagnostic for
// whether K1 is BW-bound or issue-bound).
//
// Only ~52% of voxels are ever referenced by vt (1M uniform draws over 1M
// voxels, 1-e^-0.73). A-rows have no reuse, so unreferenced rows need not
// be read at all. Pipeline:
//   prep1: flags := 0 (1MB) and vt[t] = p2v[pidx[t].y]
//   prep2: flag[vt[t]] = 1   (byte scatter; same-value races benign)
//   K1   : gemm with per-row exec-mask skip -- masked lanes issue NO
//          memory requests -> A read 536->~310 MB, feats write 64->33 MB.
//          Predicate via one coalesced flag byte/lane + __ballot (wave
//          mask in SGPR pair); per-load test is a 64-bit shift, no mem.
//   K2   : v4 4-lane-per-point gather (verified absmax 0.0), unchanged.
//
// ws layout: [0,64MB) feats | [64,68MB) vt | [68,69MB) flag
// out layout (f32): [P*16 means][P batchId][P ones]
// ---------------------------------------------------------------------------

__global__ __launch_bounds__(256) void k_prep1(
    const int* __restrict__ p2v, const int* __restrict__ prop_idx,
    int* __restrict__ vt, uint4* __restrict__ flag16)
{
    const int t = blockIdx.x * 256 + threadIdx.x;
    if (t < NUM_VOXELS / 16)                 // zero 1MB of flags as uint4
        flag16[t] = make_uint4(0u, 0u, 0u, 0u);
    if (t < TOTAL_PROP_PTS) {
        const int2* pidx2 = (const int2*)prop_idx;
        vt[t] = p2v[pidx2[t].y];
    }
}

__global__ __launch_bounds__(256) void k_prep2(
    const int* __restrict__ vt, unsigned char* __restrict__ flag)
{
    const int t = blockIdx.x * 256 + threadIdx.x;
    if (t < TOTAL_PROP_PTS) flag[vt[t]] = 1; // 1MB target, L2/L3-resident
}

__global__ __launch_bounds__(256, 4) void k_gemm_relu(
    const float* __restrict__ A, const float* __restrict__ W,
    const unsigned char* __restrict__ flag,
    float* __restrict__ feats)
{
    __shared__ float lds[4][64 * 33];
    const int wave = threadIdx.x >> 6;
    const int lane = threadIdx.x & 63;
    const int v0   = blockIdx.x * 256 + wave * 64;
    if (v0 >= NUM_VOXELS) return;            // NUM_VOXELS % 64 == 0

    const int myflag = flag[v0 + lane];      // coalesced 64B flag read
    const unsigned long long fm = __ballot(myflag != 0);
    if (fm == 0ull) return;                  // whole tile dead (p ~ 0.48^64)

    float* chunk = lds[wave];
    const float2 z2 = make_float2(0.f, 0.f);

    // K-tail cols 128..133, predicated on own-row flag
    const float* myrow = A + (size_t)(v0 + lane) * IN_CH;
    const float2 tl0 = myflag ? *(const float2*)(myrow + 128) : z2;
    const float2 tl1 = myflag ? *(const float2*)(myrow + 130) : z2;
    const float2 tl2 = myflag ? *(const float2*)(myrow + 132) : z2;

    // staging geometry: iter j stages rows 4j..4j+3; lane covers
    // (srow, col pair scol); each 16-lane quarter = 128 contiguous bytes.
    const int srow = lane >> 4;
    const int scol = (lane & 15) * 2;
    const float* sbase = A + (size_t)(v0 + srow) * IN_CH + scol;

    float2 buf[16];
#pragma unroll
    for (int j = 0; j < 16; ++j) {           // prefetch chunk 0, row-masked
        const bool want = (fm >> (j * 4 + srow)) & 1ull;
        buf[j] = want ? *(const float2*)(sbase + (size_t)j * 4 * IN_CH) : z2;
    }

    float acc[M_OUT];
#pragma unroll
    for (int c = 0; c < M_OUT; ++c) acc[c] = 0.f;

#pragma unroll
    for (int cidx = 0; cidx < 4; ++cidx) {
        const int kc = cidx * 32;
#pragma unroll
        for (int j = 0; j < 16; ++j) {       // drain staged regs into LDS
            const int row = j * 4 + srow;
            *(float2*)&chunk[row * 33 + scol] = buf[j];
        }
        if (cidx < 3) {                      // issue next chunk, row-masked
            const float* nb = sbase + kc + 32;
#pragma unroll
            for (int j = 0; j < 16; ++j) {
                const bool want = (fm >> (j * 4 + srow)) & 1ull;
                buf[j] = want ? *(const float2*)(nb + (size_t)j * 4 * IN_CH) : z2;
            }
        }
        // compute: 32 kk x (1 bank-free ds_read_b32 + 16 FMA w/ scalar W)
        const float* wbase = W + kc * M_OUT;
#pragma unroll 8
        for (int kk = 0; kk < 32; ++kk) {
            const float a = chunk[lane * 33 + kk];
            const float* wr = wbase + kk * M_OUT;
#pragma unroll
            for (int c = 0; c < M_OUT; ++c) acc[c] = fmaf(a, wr[c], acc[c]);
        }
    }
    {
        const float* wr = W + 128 * M_OUT;
#pragma unroll
        for (int c = 0; c < M_OUT; ++c) {
            float v = fmaf(tl0.x, wr[0 * M_OUT + c], acc[c]);
            v = fmaf(tl0.y, wr[1 * M_OUT + c], v);
            v = fmaf(tl1.x, wr[2 * M_OUT + c], v);
            v = fmaf(tl1.y, wr[3 * M_OUT + c], v);
            v = fmaf(tl2.x, wr[4 * M_OUT + c], v);
            acc[c] = fmaf(tl2.y, wr[5 * M_OUT + c], v);
        }
    }
    if (myflag) {                            // store only referenced rows
        float4* orow = (float4*)(feats + (size_t)(v0 + lane) * M_OUT);
#pragma unroll
        for (int q = 0; q < 4; ++q) {
            float4 o;
            o.x = fmaxf(acc[q * 4 + 0], 0.f);
            o.y = fmaxf(acc[q * 4 + 1], 0.f);
            o.z = fmaxf(acc[q * 4 + 2], 0.f);
            o.w = fmaxf(acc[q * 4 + 3], 0.f);
            orow[q] = o;
        }
    }
}

// ---------------------------------------------------------------------------
// K2 (v4, verified exact): one block per proposal, 4 lanes per point.
// One float4 instruction covers 16 points x 64 B; vt chain pipelined 1-ahead.
// ---------------------------------------------------------------------------
__global__ __launch_bounds__(256) void k_propmean(
    const float* __restrict__ feats,
    const int*   __restrict__ vt,        // [T] precomputed voxel per point
    const int*   __restrict__ prop_idx,  // [T][2] (for batchId only)
    const int*   __restrict__ offsets,   // [P+1]
    const int*   __restrict__ locs,      // [N_POINTS][4], col 0 = batch id
    float*       __restrict__ out)
{
    const int s   = blockIdx.x;
    const int tid = threadIdx.x;
    const int t0  = offsets[s];
    const int t1  = offsets[s + 1];
    const int g   = tid >> 2;
    const int q   = tid & 3;

    float a0 = 0.f, a1 = 0.f, a2 = 0.f, a3 = 0.f;

    int t = t0 + g;
    int v = (t < t1) ? vt[t] : -1;

    for (int base = t0; base < t1; base += 64) {
        const int tn = t + 64;
        const int vn = (tn < t1) ? vt[tn] : -1;   // next pass, in flight now

        if (v >= 0) {
            const float4 f = *(const float4*)(feats + (size_t)v * M_OUT + q * 4);
            a0 += f.x; a1 += f.y; a2 += f.z; a3 += f.w;
        }
        v = vn; t = tn;
    }

#pragma unroll
    for (int off = 4; off < 64; off <<= 1) {
        a0 += __shfl_down(a0, off, 64);
        a1 += __shfl_down(a1, off, 64);
        a2 += __shfl_down(a2, off, 64);
        a3 += __shfl_down(a3, off, 64);
    }

    __shared__ float red[4][4][4];       // [wave][q][elem]
    const int lane = tid & 63, wv = tid >> 6;
    if (lane < 4) {
        red[wv][lane][0] = a0; red[wv][lane][1] = a1;
        red[wv][lane][2] = a2; red[wv][lane][3] = a3;
    }
    __syncthreads();

    if (tid < M_OUT) {
        const float sum = red[0][tid >> 2][tid & 3] + red[1][tid >> 2][tid & 3]
                        + red[2][tid >> 2][tid & 3] + red[3][tid >> 2][tid & 3];
        const float cnt = (float)(t1 - t0);
        out[s * M_OUT + tid] = sum / fmaxf(cnt, 1.f);
    }
    if (tid == 0) {
        const int p = prop_idx[2 * t0 + 1];   // offsets[s] < T always
        out[NUM_PROPOSALS * M_OUT + s]                 = (float)locs[4 * p];
        out[NUM_PROPOSALS * M_OUT + NUM_PROPOSALS + s] = 1.0f;
    }
}

// ---------------------------------------------------------------------------
// Timing model: harness overhead ~= 526 us/iter (r2 calibration: 2GiB ws
// poison fill ~330 + restores ~196). v4 kernels ~= 250 us, dominated by K1.
// This round cuts K1 traffic 600->~345 MB. If dur_us doesn't drop, K1 is
// issue/latency-bound, not BW-bound -> next round restructure its inner loop.
// ---------------------------------------------------------------------------
extern "C" void kernel_launch(void* const* d_in, const int* in_sizes, int n_in,
                              void* d_out, int out_size, void* d_ws, size_t ws_size,
                              hipStream_t stream)
{
    const float* A    = (const float*)d_in[0];   // voxel_feats [1M][134]
    const float* W    = (const float*)d_in[1];   // [134][16]
    const int*   p2v  = (const int*)  d_in[2];   // [1.5M]
    const int*   pidx = (const int*)  d_in[3];   // [1M][2]
    const int*   offs = (const int*)  d_in[4];   // [2049]
    const int*   locs = (const int*)  d_in[5];   // [1.5M][4]
    float*       out  = (float*)      d_out;     // 36864 f32

    float*         feats = (float*)d_ws;
    int*           vt    = (int*)((char*)d_ws + (size_t)64 * 1024 * 1024);
    unsigned char* flag  = (unsigned char*)d_ws + (size_t)68 * 1024 * 1024;

    k_prep1<<<GP, 256, 0, stream>>>(p2v, pidx, vt, (uint4*)flag);
    k_prep2<<<GP, 256, 0, stream>>>(vt, flag);
    k_gemm_relu<<<G1, 256, 0, stream>>>(A, W, flag, feats);
    k_propmean<<<NUM_PROPOSALS, 256, 0, stream>>>(feats, vt, pidx, offs, locs, out);
}